// Round 3
// baseline (110.705 us; speedup 1.0000x reference)
//
#include <hip/hip_runtime.h>
#include <math.h>

#define NLAT 512
#define NLON 1024
#define LMAX 50
#define MMAX 50
#define NPTS 2048
#define NIMG 4                     // (branch<<1)|b : pred b0, pred b1, targ b0, targ b1
#define M_GRID (NLAT * NLON)       // 524288

#define NBT 32                     // theta bins over [0, pi]
#define NBP 64                     // phi bins over [-pi, pi]
#define NBINS (NBT * NBP)          // 2048
#define NPAIR (2 * LMAX * MMAX)    // 5000 (b,l,m) loss terms (mean divisor)
#define NTRI  (LMAX * (LMAX + 1) / 2)   // 1275 nonzero (l>=m) pairs per batch

// exact fp32 images of numpy float32 constants
#define PI_F     3.14159274101257324e0f   // (float)pi  0x40490FDB
#define TWO_PI_F 6.28318548202514648e0f   // (float)2pi 0x40C90FDB
#define WB       (PI_F / 32.0f)           // bin width (same in both axes)
#define INV_WB   (32.0f / PI_F)

// ---------------- merged setup (blocks 0..127) + per-image binning (blocks 128..131)
__global__ __launch_bounds__(256) void k_setup_bin(const float* __restrict__ pred,
                                                   const float* __restrict__ targ,
                                                   float* __restrict__ wq,
                                                   double* __restrict__ costab,
                                                   float* __restrict__ plm,
                                                   float4* __restrict__ spts_g,
                                                   unsigned short* __restrict__ bstart_g,
                                                   double* __restrict__ acc,
                                                   int* __restrict__ counter) {
    if (blockIdx.x < 128) {
        int tid = blockIdx.x * 256 + threadIdx.x;   // 0..32767
        if (tid == 0) { acc[0] = 0.0; counter[0] = 0; }

        // --- CC weights: one wave (64 lanes) per weight j
        {
            int j = blockIdx.x * 4 + (threadIdx.x >> 6);   // 0..511
            int lane = threadIdx.x & 63;
            double t = M_PI * (double)j / 511.0;
            double S = 0.0;
            for (int k = lane + 1; k <= 255; k += 64) {
                S += cos(2.0 * t * (double)k) * (2.0 / (4.0 * (double)k * k - 1.0));
            }
            for (int off = 32; off > 0; off >>= 1) S += __shfl_down(S, off);
            if (lane == 0) {
                double c = (j == 0 || j == 511) ? 1.0 : 2.0;
                wq[j] = (float)((c / 511.0) * (1.0 - S));
            }
        }
        if (tid < 1024) {
            costab[tid] = cos(2.0 * M_PI * (double)tid / 1024.0);
        }
        // --- Legendre: block b < 100 handles m = b>>1, k-half = b&1.
        // k-independent sqrt/div coefficients hoisted to LDS (bit-exact).
        if (blockIdx.x < 100) {
            __shared__ double fa[MMAX];          // fa[i] = -sqrt((2i+1)/(2i))
            __shared__ double al[LMAX], bl[LMAX];
            int m = blockIdx.x >> 1;
            int t = threadIdx.x;
            if (t >= 1 && t < MMAX) {
                fa[t] = -sqrt((2.0 * t + 1.0) / (2.0 * t));
            }
            if (t >= m + 2 && t < LMAX) {
                double ll = (double)t, mm = (double)m, lm1 = (double)(t - 1);
                al[t] = sqrt((4.0 * ll * ll - 1.0) / (ll * ll - mm * mm));
                bl[t] = sqrt((lm1 * lm1 - mm * mm) / (4.0 * lm1 * lm1 - 1.0));
            }
            __syncthreads();
            int k = ((blockIdx.x & 1) << 8) + t;          // 0..511
            double theta = M_PI * (double)k / 511.0;
            double ct = cos(theta), st = sin(theta);
            double pmm = sqrt(1.0 / (4.0 * M_PI));
            for (int i = 1; i <= m; ++i) {
                pmm = fa[i] * st * pmm;                   // ((-sqrt)*st)*pmm, as before
            }
            plm[((size_t)m * MMAX + m) * 512 + k] = (float)pmm;
            if (m + 1 < LMAX) {
                double pm1 = sqrt(2.0 * m + 3.0) * ct * pmm;
                plm[((size_t)(m + 1) * MMAX + m) * 512 + k] = (float)pm1;
                double pm2 = pmm;
                for (int l = m + 2; l < LMAX; ++l) {
                    double p = al[l] * (ct * pm1 - bl[l] * pm2);
                    plm[((size_t)l * MMAX + m) * 512 + k] = (float)p;
                    pm2 = pm1; pm1 = p;
                }
            }
        }
        return;
    }

    // ---- binning path: one block per image
    int img = blockIdx.x - 128;
    int branch = img >> 1, b = img & 1;
    const float* src = (branch ? targ : pred) + (size_t)b * NPTS * 3;
    __shared__ float sth[NPTS], sphi[NPTS], srr[NPTS];   // 24 KB
    __shared__ int cnt[NBINS];                            // 8 KB
    __shared__ int bstart[NBINS];                         // 8 KB
    __shared__ int partial[256];
    __shared__ int binid[NPTS];                           // 8 KB
    int tid = threadIdx.x;

    for (int i = tid; i < NBINS; i += 256) cnt[i] = 0;
    for (int i = tid; i < NPTS; i += 256) {
        float x = src[3 * i], y = src[3 * i + 1], z = src[3 * i + 2];
        float r = sqrtf(x * x + y * y + z * z);
        float nyz = sqrtf(y * y + z * z);
        float phi1 = acosf(x / r);
        float base = acosf(y / nyz);
        float phi2 = (z < 0.0f) ? (TWO_PI_F - base) : base;
        sth[i] = phi1; sphi[i] = phi2 - PI_F; srr[i] = r;
    }
    __syncthreads();
    for (int i = tid; i < NPTS; i += 256) {
        int bt = min(max((int)(sth[i] * INV_WB), 0), NBT - 1);
        int bp = min(max((int)((sphi[i] + PI_F) * INV_WB), 0), NBP - 1);
        int bn = bt * NBP + bp;
        binid[i] = bn;
        atomicAdd(&cnt[bn], 1);
    }
    __syncthreads();
    // exclusive scan over 2048 bins: 8 bins per thread + scan of 256 partials
    int base = tid * 8, s = 0;
    #pragma unroll
    for (int j = 0; j < 8; ++j) s += cnt[base + j];
    partial[tid] = s;
    __syncthreads();
    for (int offs = 1; offs < 256; offs <<= 1) {
        int v = (tid >= offs) ? partial[tid - offs] : 0;
        __syncthreads();
        partial[tid] += v;
        __syncthreads();
    }
    int run = (tid == 0) ? 0 : partial[tid - 1];
    #pragma unroll
    for (int j = 0; j < 8; ++j) { bstart[base + j] = run; run += cnt[base + j]; }
    __syncthreads();
    unsigned short* bsg = bstart_g + (size_t)img * (NBINS + 1);
    for (int i = tid; i < NBINS; i += 256) {
        bsg[i] = (unsigned short)bstart[i];
        cnt[i] = bstart[i];
    }
    if (tid == 0) bsg[NBINS] = (unsigned short)NPTS;
    __syncthreads();
    float4* sg = spts_g + (size_t)img * NPTS;
    for (int i = tid; i < NPTS; i += 256) {
        int bn = binid[i];
        int pos = atomicAdd(&cnt[bn], 1);   // within-bin order nondeterministic; value-safe
        sg[pos] = make_float4(sth[i], sphi[i], srr[i], 0.0f);
    }
}

// ---------------- binned 3-NN + interp: one WAVE per 8x16 patch (2 queries/lane),
// row-span ring scan, 512-thread blocks (4 blocks/CU -> full occupancy)
__global__ __launch_bounds__(512, 8) void k_nn(const float4* __restrict__ spts_g,
                                               const unsigned short* __restrict__ bstart_g,
                                               float* __restrict__ interp) {
    __shared__ float4 spts[NPTS];                  // 32 KB
    __shared__ unsigned short sstart[NBINS + 1];   // 4 KB
    int bid = blockIdx.x;
    int img = bid >> 9;                            // 512 blocks per image
    int blk = bid & 511;
    const float4* sg = spts_g + (size_t)img * NPTS;
    const unsigned short* bsg = bstart_g + (size_t)img * (NBINS + 1);
    int tid = threadIdx.x;
    for (int i = tid; i < NPTS; i += 512) spts[i] = sg[i];
    for (int i = tid; i < NBINS + 1; i += 512) sstart[i] = bsg[i];
    __syncthreads();

    // 8 waves/block; wave w -> patch blk*8+w of a 64x64 grid of 8(theta)x16(phi) patches
    int w = tid >> 6, lane = tid & 63;
    int patch = blk * 8 + w;
    int pi = patch >> 6, pj = patch & 63;
    int qi = lane >> 3, qj0 = (lane & 7) * 2;      // two phi-adjacent queries per lane
    int gi = pi * 8 + qi;
    int gj0 = pj * 16 + qj0, gj1 = gj0 + 1;
    float gt  = (float)gi * (1.0f / 512.0f) * PI_F;
    float gp0 = (float)(gj0 - 512) * (1.0f / 512.0f) * PI_F;   // independent rounding:
    float gp1 = (float)(gj1 - 512) * (1.0f / 512.0f) * PI_F;   // exact fp32 ref match
    int qbt  = min(max((int)(gt * INV_WB), 0), NBT - 1);
    int qbp0 = min(max((int)((gp0 + PI_F) * INV_WB), 0), NBP - 1);
    int qbp1 = min(max((int)((gp1 + PI_F) * INV_WB), 0), NBP - 1);
    // binning monotone in gi/gj -> lane 0 query0 is bbox min, lane 63 query1 is bbox max
    int bt0 = __shfl(qbt, 0), bt1 = __shfl(qbt, 63);
    int bp0 = __shfl(qbp0, 0), bp1 = __shfl(qbp1, 63);

    float da0 = 1e30f, da1 = 1e30f, da2 = 1e30f;   // top-3 for query A (gp0)
    float ra0 = 0.0f, ra1 = 0.0f, ra2 = 0.0f;
    float db0 = 1e30f, db1 = 1e30f, db2 = 1e30f;   // top-3 for query B (gp1)
    float rb0 = 0.0f, rb1 = 0.0f, rb2 = 0.0f;

    // sorted 3-slot insert; all-false conditions leave state unchanged (no-op safe)
    auto ins = [](float d, float rv, float& d0, float& d1, float& d2,
                  float& r0, float& r1, float& r2) {
        bool c2 = d < d2, c1 = d < d1, c0 = d < d0;
        d2 = c1 ? d1 : (c2 ? d : d2);   r2 = c1 ? r1 : (c2 ? rv : r2);
        d1 = c0 ? d0 : (c1 ? d : d1);   r1 = c0 ? r0 : (c1 ? rv : r1);
        d0 = c0 ? d : d0;               r0 = c0 ? rv : r0;
    };

    // contiguous point-span over bins (t, p0..p1): counting-sort layout is bin-major,
    // so one row of bins = one span. Point sequence identical to per-bin scanning.
    // unroll 2: two independent ds_read_b128 + distance chains per trip (ILP);
    // insert order preserved -> bit-identical results.
    auto scan_span = [&](int t, int p0, int p1) {
        int s = sstart[t * NBP + p0], e = sstart[t * NBP + p1 + 1];
        #pragma unroll 2
        for (int i = s; i < e; ++i) {
            float4 pt = spts[i];                   // wave-uniform LDS read: broadcast
            float dx  = gt - pt.x;
            float dxx = dx * dx;
            float dy0 = gp0 - pt.y;
            float dy1 = gp1 - pt.y;
            float dA  = fmaf(dy0, dy0, dxx);
            float dB  = fmaf(dy1, dy1, dxx);
            // split A/B gating: skip a 13-instr chain when only one side improves
            if (__any(dA < da2)) {
                ins(dA, pt.z, da0, da1, da2, ra0, ra1, ra2);
            }
            if (__any(dB < db2)) {
                ins(dB, pt.z, db0, db1, db2, rb0, rb1, rb2);
            }
        }
    };

    // r = 0: bbox rows
    for (int t = bt0; t <= bt1; ++t) scan_span(t, bp0, bp1);
    const float INF = 1e30f;
    for (int r = 1; r <= 70; ++r) {
        // per-lane stop bound: rings 0..r-1 complete -> unscanned region lies
        // outside the box theta in [TLO,THI), phi in [PLO,PHI). Query is inside,
        // so dist(query, unscanned) >= min over ACTIVE sides of coord distance.
        // Clamped (fully scanned) sides contribute +inf; if all sides clamped,
        // bnd=inf -> bnd^2=inf -> da2<=inf -> break (full coverage, correct).
        // Value-safe: we stop only when every unscanned point provably fails the
        // strict `<` insert for every lane (da2 <= bnd^2, 0.999 fp guard).
        {
            float tL = (bt0 - r + 1 > 0)    ? gt - (float)(bt0 - r + 1) * WB : INF;
            float tH = (bt1 + r <= NBT - 1) ? (float)(bt1 + r) * WB - gt     : INF;
            bool  loP = (bp0 - r + 1 > 0);
            bool  hiP = (bp1 + r <= NBP - 1);
            float pLc = (float)(bp0 - r + 1) * WB - PI_F;   // unscanned: phi <  pLc
            float pHc = (float)(bp1 + r) * WB - PI_F;       // unscanned: phi >= pHc
            float pLa = loP ? gp0 - pLc : INF;
            float pHa = hiP ? pHc - gp0 : INF;
            float pLb = loP ? gp1 - pLc : INF;
            float pHb = hiP ? pHc - gp1 : INF;
            float tmin = fminf(tL, tH);
            float bA = fminf(tmin, fminf(pLa, pHa)) * 0.999f;
            float bB = fminf(tmin, fminf(pLb, pHb)) * 0.999f;
            if (__all(da2 <= bA * bA && db2 <= bB * bB)) break;
        }
        int tlo = bt0 - r, thi = bt1 + r, plo = bp0 - r, phi = bp1 + r;
        int cplo = max(plo, 0), cphi = min(phi, NBP - 1);
        if (tlo >= 0)       scan_span(tlo, cplo, cphi);
        if (thi <= NBT - 1) scan_span(thi, cplo, cphi);
        int ctlo = max(tlo + 1, 0), cthi = min(thi - 1, NBT - 1);
        if (plo >= 0)       for (int t = ctlo; t <= cthi; ++t) scan_span(t, plo, plo);
        if (phi <= NBP - 1) for (int t = ctlo; t <= cthi; ++t) scan_span(t, phi, phi);
        if (tlo <= 0 && thi >= NBT - 1 && plo <= 0 && phi >= NBP - 1) break;
    }
    float sA = da0 + da1 + da2;     // faithful: weights proportional to distance
    float sB = db0 + db1 + db2;
    float2 outv;
    outv.x = (da0 * ra0 + da1 * ra1 + da2 * ra2) / sA;
    outv.y = (db0 * rb0 + db1 * rb1 + db2 * rb2) / sB;
    *(float2*)&interp[(size_t)img * M_GRID + (size_t)gi * NLON + gj0] = outv;
}

// ---------------- DFT of the DIFFERENCE field (SHT is linear): E[b,m,k] =
// wq[k]*(2pi/N)*Re rfft(interp[pred,b]-interp[targ,b])[k,m].  1024 rows, 8 waves/blk.
__global__ __launch_bounds__(512) void k_dft(const float* __restrict__ interp,
                                             const double* __restrict__ costab,
                                             const float* __restrict__ wq,
                                             double* __restrict__ ediff) {
    __shared__ double sdf[NLON];     // 8 KB: fp64 diff of the two fp32 rows
    __shared__ double sct[NLON];     // 8 KB
    __shared__ double g[576];        // 4.5 KB (g[513..575] = 0 pad)
    int bid = blockIdx.x;            // one block per (batch, k) row: 1024 rows
    int b = bid >> 9, k = bid & 511;
    const float* rowp = interp + (size_t)b * M_GRID + (size_t)k * NLON;        // pred
    const float* rowt = interp + (size_t)(2 + b) * M_GRID + (size_t)k * NLON;  // targ
    int tid = threadIdx.x;
    for (int i = tid; i < NLON; i += 512) {
        sdf[i] = (double)rowp[i] - (double)rowt[i];   // exact in fp64
        sct[i] = costab[i];
    }
    __syncthreads();
    // fold: g[n] = d[n] + d[1024-n] (n=1..511), g[0]=d[0], g[512]=d[512]
    for (int n = tid; n < 576; n += 512) {
        double v = 0.0;
        if (n == 0) v = sdf[0];
        else if (n < 512) v = sdf[n] + sdf[1024 - n];
        else if (n == 512) v = sdf[512];
        g[n] = v;
    }
    __syncthreads();
    double scale = (double)wq[k] * (6.283185307179586 / 1024.0);
    int w = tid >> 6, lane = tid & 63;
    for (int m = w; m < MMAX; m += 8) {
        // cos/sin at theta = 2*pi*m*lane/1024; sin(x) = cos(x - pi/2) -> idx +768
        double c  = sct[(m * lane) & 1023];
        double s  = sct[(m * lane + 768) & 1023];
        double cd = sct[(m * 64) & 1023];          // rotation by delta = 2*pi*m*64/1024
        double sd = sct[(m * 64 + 768) & 1023];
        double a = 0.0;
        #pragma unroll
        for (int i = 0; i < 9; ++i) {
            int n = lane + (i << 6);               // lane-consecutive: conflict-free
            a = fma(g[n], c, a);
            double cn = fma(cd, c, -(sd * s));
            double sn = fma(cd, s, sd * c);
            c = cn; s = sn;
        }
        #pragma unroll
        for (int off = 32; off > 0; off >>= 1) a += __shfl_xor(a, off);
        if (lane == 0) {
            ediff[((size_t)b * MMAX + m) * 512 + k] = a * scale;
        }
    }
}

// ---------------- Legendre contraction of diff coeffs + loss; last block writes out.
// Only l >= m triples: P_l^m == 0 for l < m (reference zero-fills), so half the
// naive grid would compute exactly-zero terms. Triangular decode; mean still
// divides by the full NPAIR = 5000.
__global__ __launch_bounds__(256) void k_loss(const double* __restrict__ ediff,
                                              const float* __restrict__ plm,
                                              double* __restrict__ acc,
                                              int* __restrict__ counter,
                                              float* __restrict__ out) {
    int tid = threadIdx.x;
    int gtid = blockIdx.x * 256 + tid;
    int triple = gtid >> 4, j = gtid & 15;         // 16 lanes per (b, l>=m pair)
    double c = 0.0;
    int valid = (triple < 2 * NTRI);
    {
        int b = triple / NTRI;
        int p = triple % NTRI;                     // p = l*(l+1)/2 + m, l in [0,50)
        int l = (int)((sqrtf(8.0f * (float)p + 1.0f) - 1.0f) * 0.5f);
        while ((l + 1) * (l + 2) / 2 <= p) ++l;    // fix float-rounding off-by-one
        while (l * (l + 1) / 2 > p) --l;
        int m = p - l * (l + 1) / 2;
        if (valid) {
            const double* E = ediff + ((size_t)b * MMAX + m) * 512;
            const float*  P = plm + ((size_t)l * MMAX + m) * 512;
            for (int i = 0; i < 32; ++i) {
                int k = j + (i << 4);
                c = fma((double)P[k], E[k], c);
            }
        }
    }
    c += __shfl_xor(c, 1);
    c += __shfl_xor(c, 2);
    c += __shfl_xor(c, 4);
    c += __shfl_xor(c, 8);
    __shared__ double red[16];
    if (j == 0) red[tid >> 4] = valid ? c * c : 0.0;
    __syncthreads();
    if (tid == 0) {
        double s = 0.0;
        for (int i = 0; i < 16; ++i) s += red[i];
        atomicAdd(acc, s);                      // device-scope, coherent across XCDs
        __threadfence();
        int old = atomicAdd(counter, 1);
        if (old == (int)gridDim.x - 1) {
            double tot = atomicAdd(acc, 0.0);   // coherent read of final sum
            out[0] = (float)(tot / (double)NPAIR);
        }
    }
}

extern "C" void kernel_launch(void* const* d_in, const int* in_sizes, int n_in,
                              void* d_out, int out_size, void* d_ws, size_t ws_size,
                              hipStream_t stream) {
    const float* pred = (const float*)d_in[0];
    const float* targ = (const float*)d_in[1];

    char* ws = (char*)d_ws;
    size_t off = 0;
    auto alloc = [&](size_t bytes) -> void* {
        void* p = ws + off;
        off = (off + bytes + 255) & ~(size_t)255;
        return p;
    };
    float*  wq      = (float*) alloc(512 * sizeof(float));
    double* costab  = (double*)alloc(1024 * sizeof(double));
    float*  plm     = (float*) alloc((size_t)LMAX * MMAX * 512 * sizeof(float));
    float4* spts    = (float4*)alloc((size_t)NIMG * NPTS * sizeof(float4));
    unsigned short* bstart = (unsigned short*)alloc((size_t)NIMG * (NBINS + 1) * sizeof(unsigned short));
    float*  interp  = (float*) alloc((size_t)NIMG * M_GRID * sizeof(float));
    double* ediff   = (double*)alloc((size_t)2 * MMAX * 512 * sizeof(double));
    double* acc     = (double*)alloc(sizeof(double));
    int*    counter = (int*)   alloc(sizeof(int));
    (void)ws_size; (void)in_sizes; (void)n_in; (void)out_size;

    k_setup_bin<<<132, 256, 0, stream>>>(pred, targ, wq, costab, plm, spts, bstart,
                                         acc, counter);
    k_nn<<<NIMG * 512, 512, 0, stream>>>(spts, bstart, interp);
    k_dft<<<2 * 512, 512, 0, stream>>>(interp, costab, wq, ediff);
    int nb = (2 * NTRI * 16 + 255) / 256;   // 160 blocks, l>=m only
    k_loss<<<nb, 256, 0, stream>>>(ediff, plm, acc, counter, (float*)d_out);
}

// Round 4
// 106.530 us; speedup vs baseline: 1.0392x; 1.0392x over previous
//
#include <hip/hip_runtime.h>
#include <math.h>

#define NLAT 512
#define NLON 1024
#define LMAX 50
#define MMAX 50
#define NPTS 2048
#define NIMG 4                     // (branch<<1)|b : pred b0, pred b1, targ b0, targ b1
#define M_GRID (NLAT * NLON)       // 524288

#define NBT 32                     // theta bins over [0, pi]
#define NBP 64                     // phi bins over [-pi, pi]
#define NBINS (NBT * NBP)          // 2048
#define NPAIR (2 * LMAX * MMAX)    // 5000 (b,l,m) loss terms (mean divisor)
#define NTRI  (LMAX * (LMAX + 1) / 2)   // 1275 nonzero (l>=m) pairs per batch

// exact fp32 images of numpy float32 constants
#define PI_F     3.14159274101257324e0f   // (float)pi  0x40490FDB
#define TWO_PI_F 6.28318548202514648e0f   // (float)2pi 0x40C90FDB
#define WB       (PI_F / 32.0f)           // bin width (same in both axes)
#define INV_WB   (32.0f / PI_F)

// ---------------- merged setup (blocks 0..127) + per-image binning (blocks 128..131)
__global__ __launch_bounds__(256) void k_setup_bin(const float* __restrict__ pred,
                                                   const float* __restrict__ targ,
                                                   float* __restrict__ wq,
                                                   double* __restrict__ costab,
                                                   float* __restrict__ plm,
                                                   float4* __restrict__ spts_g,
                                                   unsigned short* __restrict__ bstart_g,
                                                   double* __restrict__ acc,
                                                   int* __restrict__ counter) {
    if (blockIdx.x < 128) {
        int tid = blockIdx.x * 256 + threadIdx.x;   // 0..32767
        if (tid == 0) { acc[0] = 0.0; counter[0] = 0; }

        // --- CC weights: one wave (64 lanes) per weight j
        {
            int j = blockIdx.x * 4 + (threadIdx.x >> 6);   // 0..511
            int lane = threadIdx.x & 63;
            double t = M_PI * (double)j / 511.0;
            double S = 0.0;
            for (int k = lane + 1; k <= 255; k += 64) {
                S += cos(2.0 * t * (double)k) * (2.0 / (4.0 * (double)k * k - 1.0));
            }
            for (int off = 32; off > 0; off >>= 1) S += __shfl_down(S, off);
            if (lane == 0) {
                double c = (j == 0 || j == 511) ? 1.0 : 2.0;
                wq[j] = (float)((c / 511.0) * (1.0 - S));
            }
        }
        if (tid < 1024) {
            costab[tid] = cos(2.0 * M_PI * (double)tid / 1024.0);
        }
        // --- Legendre: block b < 100 handles m = b>>1, k-half = b&1.
        // k-independent sqrt/div coefficients hoisted to LDS (bit-exact).
        if (blockIdx.x < 100) {
            __shared__ double fa[MMAX];          // fa[i] = -sqrt((2i+1)/(2i))
            __shared__ double al[LMAX], bl[LMAX];
            int m = blockIdx.x >> 1;
            int t = threadIdx.x;
            if (t >= 1 && t < MMAX) {
                fa[t] = -sqrt((2.0 * t + 1.0) / (2.0 * t));
            }
            if (t >= m + 2 && t < LMAX) {
                double ll = (double)t, mm = (double)m, lm1 = (double)(t - 1);
                al[t] = sqrt((4.0 * ll * ll - 1.0) / (ll * ll - mm * mm));
                bl[t] = sqrt((lm1 * lm1 - mm * mm) / (4.0 * lm1 * lm1 - 1.0));
            }
            __syncthreads();
            int k = ((blockIdx.x & 1) << 8) + t;          // 0..511
            double theta = M_PI * (double)k / 511.0;
            double ct = cos(theta), st = sin(theta);
            double pmm = sqrt(1.0 / (4.0 * M_PI));
            for (int i = 1; i <= m; ++i) {
                pmm = fa[i] * st * pmm;                   // ((-sqrt)*st)*pmm, as before
            }
            plm[((size_t)m * MMAX + m) * 512 + k] = (float)pmm;
            if (m + 1 < LMAX) {
                double pm1 = sqrt(2.0 * m + 3.0) * ct * pmm;
                plm[((size_t)(m + 1) * MMAX + m) * 512 + k] = (float)pm1;
                double pm2 = pmm;
                for (int l = m + 2; l < LMAX; ++l) {
                    double p = al[l] * (ct * pm1 - bl[l] * pm2);
                    plm[((size_t)l * MMAX + m) * 512 + k] = (float)p;
                    pm2 = pm1; pm1 = p;
                }
            }
        }
        return;
    }

    // ---- binning path: one block per image
    int img = blockIdx.x - 128;
    int branch = img >> 1, b = img & 1;
    const float* src = (branch ? targ : pred) + (size_t)b * NPTS * 3;
    __shared__ float sth[NPTS], sphi[NPTS], srr[NPTS];   // 24 KB
    __shared__ int cnt[NBINS];                            // 8 KB
    __shared__ int bstart[NBINS];                         // 8 KB
    __shared__ int partial[256];
    __shared__ int binid[NPTS];                           // 8 KB
    int tid = threadIdx.x;

    for (int i = tid; i < NBINS; i += 256) cnt[i] = 0;
    for (int i = tid; i < NPTS; i += 256) {
        float x = src[3 * i], y = src[3 * i + 1], z = src[3 * i + 2];
        float r = sqrtf(x * x + y * y + z * z);
        float nyz = sqrtf(y * y + z * z);
        float phi1 = acosf(x / r);
        float base = acosf(y / nyz);
        float phi2 = (z < 0.0f) ? (TWO_PI_F - base) : base;
        sth[i] = phi1; sphi[i] = phi2 - PI_F; srr[i] = r;
    }
    __syncthreads();
    for (int i = tid; i < NPTS; i += 256) {
        int bt = min(max((int)(sth[i] * INV_WB), 0), NBT - 1);
        int bp = min(max((int)((sphi[i] + PI_F) * INV_WB), 0), NBP - 1);
        int bn = bt * NBP + bp;
        binid[i] = bn;
        atomicAdd(&cnt[bn], 1);
    }
    __syncthreads();
    // exclusive scan over 2048 bins: 8 bins per thread + scan of 256 partials
    int base = tid * 8, s = 0;
    #pragma unroll
    for (int j = 0; j < 8; ++j) s += cnt[base + j];
    partial[tid] = s;
    __syncthreads();
    for (int offs = 1; offs < 256; offs <<= 1) {
        int v = (tid >= offs) ? partial[tid - offs] : 0;
        __syncthreads();
        partial[tid] += v;
        __syncthreads();
    }
    int run = (tid == 0) ? 0 : partial[tid - 1];
    #pragma unroll
    for (int j = 0; j < 8; ++j) { bstart[base + j] = run; run += cnt[base + j]; }
    __syncthreads();
    unsigned short* bsg = bstart_g + (size_t)img * (NBINS + 1);
    for (int i = tid; i < NBINS; i += 256) {
        bsg[i] = (unsigned short)bstart[i];
        cnt[i] = bstart[i];
    }
    if (tid == 0) bsg[NBINS] = (unsigned short)NPTS;
    __syncthreads();
    float4* sg = spts_g + (size_t)img * NPTS;
    for (int i = tid; i < NPTS; i += 256) {
        int bn = binid[i];
        int pos = atomicAdd(&cnt[bn], 1);   // within-bin order nondeterministic; value-safe
        sg[pos] = make_float4(sth[i], sphi[i], srr[i], 0.0f);
    }
}

// per-query top-3 state; static member access only -> stays in VGPRs
struct Top3 {
    float d0, d1, d2, r0, r1, r2;
    __device__ void init() { d0 = d1 = d2 = 1e30f; r0 = r1 = r2 = 0.0f; }
    __device__ void ins(float d, float rv) {
        bool c2 = d < d2, c1 = d < d1, c0 = d < d0;
        d2 = c1 ? d1 : (c2 ? d : d2);   r2 = c1 ? r1 : (c2 ? rv : r2);
        d1 = c0 ? d0 : (c1 ? d : d1);   r1 = c0 ? r0 : (c1 ? rv : r1);
        d0 = c0 ? d : d0;               r0 = c0 ? rv : r0;
    }
    __device__ float out() const {      // faithful: weights proportional to distance
        return (d0 * r0 + d1 * r1 + d2 * r2) / (d0 + d1 + d2);
    }
};

// ---------------- binned 3-NN + interp: one WAVE per 16x16 patch (4 queries/lane),
// row-span ring scan. 4 queries amortize the shared dx^2, ring bookkeeping, and
// LDS broadcast reads over 2x the output vs the old 8x16/2-query layout; wave
// count halves (8K total), spts staging halves, grid = exactly 4 blocks/CU.
// Per-query arithmetic and point scan order are bit-identical to the 2-query
// version. launch_bounds min-waves=4: floor not cap — avoids spill-fitting.
__global__ __launch_bounds__(512, 4) void k_nn(const float4* __restrict__ spts_g,
                                               const unsigned short* __restrict__ bstart_g,
                                               float* __restrict__ interp) {
    __shared__ float4 spts[NPTS];                  // 32 KB
    __shared__ unsigned short sstart[NBINS + 1];   // 4 KB
    int bid = blockIdx.x;
    int img = bid >> 8;                            // 256 blocks per image
    int blk = bid & 255;
    const float4* sg = spts_g + (size_t)img * NPTS;
    const unsigned short* bsg = bstart_g + (size_t)img * (NBINS + 1);
    int tid = threadIdx.x;
    for (int i = tid; i < NPTS; i += 512) spts[i] = sg[i];
    for (int i = tid; i < NBINS + 1; i += 512) sstart[i] = bsg[i];
    __syncthreads();

    // 8 waves/block; wave w -> patch blk*8+w of a 32x64 grid of 16x16 patches
    int w = tid >> 6, lane = tid & 63;
    int patch = blk * 8 + w;
    int pi = patch >> 6, pj = patch & 63;          // 32 x 64 patches
    int qi = lane >> 2, qj0 = (lane & 3) * 4;      // four phi-adjacent queries per lane
    int gi = pi * 16 + qi;
    int gj0 = pj * 16 + qj0;
    float gt  = (float)gi * (1.0f / 512.0f) * PI_F;
    // independent per-column rounding: exact fp32 ref match
    float gp0 = (float)(gj0     - 512) * (1.0f / 512.0f) * PI_F;
    float gp1 = (float)(gj0 + 1 - 512) * (1.0f / 512.0f) * PI_F;
    float gp2 = (float)(gj0 + 2 - 512) * (1.0f / 512.0f) * PI_F;
    float gp3 = (float)(gj0 + 3 - 512) * (1.0f / 512.0f) * PI_F;
    int qbt  = min(max((int)(gt * INV_WB), 0), NBT - 1);
    int qbp0 = min(max((int)((gp0 + PI_F) * INV_WB), 0), NBP - 1);
    int qbp3 = min(max((int)((gp3 + PI_F) * INV_WB), 0), NBP - 1);
    // binning monotone in gi/gj -> lane 0 query0 is bbox min, lane 63 query3 is bbox max
    int bt0 = __shfl(qbt, 0), bt1 = __shfl(qbt, 63);
    int bp0 = __shfl(qbp0, 0), bp1 = __shfl(qbp3, 63);

    Top3 qA, qB, qC, qD;
    qA.init(); qB.init(); qC.init(); qD.init();

    // contiguous point-span over bins (t, p0..p1): counting-sort layout is bin-major,
    // so one row of bins = one span. Point sequence identical to per-bin scanning.
    // unroll 2: two independent ds_read_b128 + distance chains per trip (ILP).
    auto scan_span = [&](int t, int p0, int p1) {
        int s = sstart[t * NBP + p0], e = sstart[t * NBP + p1 + 1];
        #pragma unroll 2
        for (int i = s; i < e; ++i) {
            float4 pt = spts[i];                   // wave-uniform LDS read: broadcast
            float dx  = gt - pt.x;
            float dxx = dx * dx;
            float dy0 = gp0 - pt.y;
            float dy1 = gp1 - pt.y;
            float dy2 = gp2 - pt.y;
            float dy3 = gp3 - pt.y;
            float dA  = fmaf(dy0, dy0, dxx);
            float dB  = fmaf(dy1, dy1, dxx);
            float dC  = fmaf(dy2, dy2, dxx);
            float dD  = fmaf(dy3, dy3, dxx);
            // paired gating: skip two insert chains when neither of a pair improves
            if (__any(dA < qA.d2 || dB < qB.d2)) {
                qA.ins(dA, pt.z);
                qB.ins(dB, pt.z);
            }
            if (__any(dC < qC.d2 || dD < qD.d2)) {
                qC.ins(dC, pt.z);
                qD.ins(dD, pt.z);
            }
        }
    };

    // r = 0: bbox rows
    for (int t = bt0; t <= bt1; ++t) scan_span(t, bp0, bp1);
    for (int r = 1; r <= 70; ++r) {
        if (r >= 2) {
            // rings 0..r-1 complete: unscanned points are >= (r-1)*WB away
            // (d2 = 1e30 until 3 inserts -> bound test fails automatically)
            float bnd = (float)(r - 1) * WB * 0.999f;
            float b2 = bnd * bnd;
            if (__all(b2 > qA.d2 && b2 > qB.d2 && b2 > qC.d2 && b2 > qD.d2)) break;
        }
        int tlo = bt0 - r, thi = bt1 + r, plo = bp0 - r, phi = bp1 + r;
        int cplo = max(plo, 0), cphi = min(phi, NBP - 1);
        if (tlo >= 0)       scan_span(tlo, cplo, cphi);
        if (thi <= NBT - 1) scan_span(thi, cplo, cphi);
        int ctlo = max(tlo + 1, 0), cthi = min(thi - 1, NBT - 1);
        if (plo >= 0)       for (int t = ctlo; t <= cthi; ++t) scan_span(t, plo, plo);
        if (phi <= NBP - 1) for (int t = ctlo; t <= cthi; ++t) scan_span(t, phi, phi);
        if (tlo <= 0 && thi >= NBT - 1 && plo <= 0 && phi >= NBP - 1) break;
    }
    float4 outv = make_float4(qA.out(), qB.out(), qC.out(), qD.out());
    *(float4*)&interp[(size_t)img * M_GRID + (size_t)gi * NLON + gj0] = outv;
}

// ---------------- DFT of the DIFFERENCE field (SHT is linear): E[b,m,k] =
// wq[k]*(2pi/N)*Re rfft(interp[pred,b]-interp[targ,b])[k,m].  1024 rows, 8 waves/blk.
__global__ __launch_bounds__(512) void k_dft(const float* __restrict__ interp,
                                             const double* __restrict__ costab,
                                             const float* __restrict__ wq,
                                             double* __restrict__ ediff) {
    __shared__ double sdf[NLON];     // 8 KB: fp64 diff of the two fp32 rows
    __shared__ double sct[NLON];     // 8 KB
    __shared__ double g[576];        // 4.5 KB (g[513..575] = 0 pad)
    int bid = blockIdx.x;            // one block per (batch, k) row: 1024 rows
    int b = bid >> 9, k = bid & 511;
    const float* rowp = interp + (size_t)b * M_GRID + (size_t)k * NLON;        // pred
    const float* rowt = interp + (size_t)(2 + b) * M_GRID + (size_t)k * NLON;  // targ
    int tid = threadIdx.x;
    for (int i = tid; i < NLON; i += 512) {
        sdf[i] = (double)rowp[i] - (double)rowt[i];   // exact in fp64
        sct[i] = costab[i];
    }
    __syncthreads();
    // fold: g[n] = d[n] + d[1024-n] (n=1..511), g[0]=d[0], g[512]=d[512]
    for (int n = tid; n < 576; n += 512) {
        double v = 0.0;
        if (n == 0) v = sdf[0];
        else if (n < 512) v = sdf[n] + sdf[1024 - n];
        else if (n == 512) v = sdf[512];
        g[n] = v;
    }
    __syncthreads();
    double scale = (double)wq[k] * (6.283185307179586 / 1024.0);
    int w = tid >> 6, lane = tid & 63;
    for (int m = w; m < MMAX; m += 8) {
        // cos/sin at theta = 2*pi*m*lane/1024; sin(x) = cos(x - pi/2) -> idx +768
        double c  = sct[(m * lane) & 1023];
        double s  = sct[(m * lane + 768) & 1023];
        double cd = sct[(m * 64) & 1023];          // rotation by delta = 2*pi*m*64/1024
        double sd = sct[(m * 64 + 768) & 1023];
        double a = 0.0;
        #pragma unroll
        for (int i = 0; i < 9; ++i) {
            int n = lane + (i << 6);               // lane-consecutive: conflict-free
            a = fma(g[n], c, a);
            double cn = fma(cd, c, -(sd * s));
            double sn = fma(cd, s, sd * c);
            c = cn; s = sn;
        }
        #pragma unroll
        for (int off = 32; off > 0; off >>= 1) a += __shfl_xor(a, off);
        if (lane == 0) {
            ediff[((size_t)b * MMAX + m) * 512 + k] = a * scale;
        }
    }
}

// ---------------- Legendre contraction of diff coeffs + loss; last block writes out.
// Only l >= m triples: P_l^m == 0 for l < m (reference zero-fills), so half the
// naive grid would compute exactly-zero terms. Triangular decode; mean still
// divides by the full NPAIR = 5000.
__global__ __launch_bounds__(256) void k_loss(const double* __restrict__ ediff,
                                              const float* __restrict__ plm,
                                              double* __restrict__ acc,
                                              int* __restrict__ counter,
                                              float* __restrict__ out) {
    int tid = threadIdx.x;
    int gtid = blockIdx.x * 256 + tid;
    int triple = gtid >> 4, j = gtid & 15;         // 16 lanes per (b, l>=m pair)
    double c = 0.0;
    int valid = (triple < 2 * NTRI);
    {
        int b = triple / NTRI;
        int p = triple % NTRI;                     // p = l*(l+1)/2 + m, l in [0,50)
        int l = (int)((sqrtf(8.0f * (float)p + 1.0f) - 1.0f) * 0.5f);
        while ((l + 1) * (l + 2) / 2 <= p) ++l;    // fix float-rounding off-by-one
        while (l * (l + 1) / 2 > p) --l;
        int m = p - l * (l + 1) / 2;
        if (valid) {
            const double* E = ediff + ((size_t)b * MMAX + m) * 512;
            const float*  P = plm + ((size_t)l * MMAX + m) * 512;
            for (int i = 0; i < 32; ++i) {
                int k = j + (i << 4);
                c = fma((double)P[k], E[k], c);
            }
        }
    }
    c += __shfl_xor(c, 1);
    c += __shfl_xor(c, 2);
    c += __shfl_xor(c, 4);
    c += __shfl_xor(c, 8);
    __shared__ double red[16];
    if (j == 0) red[tid >> 4] = valid ? c * c : 0.0;
    __syncthreads();
    if (tid == 0) {
        double s = 0.0;
        for (int i = 0; i < 16; ++i) s += red[i];
        atomicAdd(acc, s);                      // device-scope, coherent across XCDs
        __threadfence();
        int old = atomicAdd(counter, 1);
        if (old == (int)gridDim.x - 1) {
            double tot = atomicAdd(acc, 0.0);   // coherent read of final sum
            out[0] = (float)(tot / (double)NPAIR);
        }
    }
}

extern "C" void kernel_launch(void* const* d_in, const int* in_sizes, int n_in,
                              void* d_out, int out_size, void* d_ws, size_t ws_size,
                              hipStream_t stream) {
    const float* pred = (const float*)d_in[0];
    const float* targ = (const float*)d_in[1];

    char* ws = (char*)d_ws;
    size_t off = 0;
    auto alloc = [&](size_t bytes) -> void* {
        void* p = ws + off;
        off = (off + bytes + 255) & ~(size_t)255;
        return p;
    };
    float*  wq      = (float*) alloc(512 * sizeof(float));
    double* costab  = (double*)alloc(1024 * sizeof(double));
    float*  plm     = (float*) alloc((size_t)LMAX * MMAX * 512 * sizeof(float));
    float4* spts    = (float4*)alloc((size_t)NIMG * NPTS * sizeof(float4));
    unsigned short* bstart = (unsigned short*)alloc((size_t)NIMG * (NBINS + 1) * sizeof(unsigned short));
    float*  interp  = (float*) alloc((size_t)NIMG * M_GRID * sizeof(float));
    double* ediff   = (double*)alloc((size_t)2 * MMAX * 512 * sizeof(double));
    double* acc     = (double*)alloc(sizeof(double));
    int*    counter = (int*)   alloc(sizeof(int));
    (void)ws_size; (void)in_sizes; (void)n_in; (void)out_size;

    k_setup_bin<<<132, 256, 0, stream>>>(pred, targ, wq, costab, plm, spts, bstart,
                                         acc, counter);
    k_nn<<<NIMG * 256, 512, 0, stream>>>(spts, bstart, interp);
    k_dft<<<2 * 512, 512, 0, stream>>>(interp, costab, wq, ediff);
    int nb = (2 * NTRI * 16 + 255) / 256;   // 160 blocks, l>=m only
    k_loss<<<nb, 256, 0, stream>>>(ediff, plm, acc, counter, (float*)d_out);
}